// Round 5
// baseline (538.694 us; speedup 1.0000x reference)
//
#include <hip/hip_runtime.h>

typedef __bf16 bf16x8 __attribute__((ext_vector_type(8)));
typedef float f32x4 __attribute__((ext_vector_type(4)));
typedef short short8 __attribute__((ext_vector_type(8)));

__device__ __forceinline__ unsigned short f2bf_u(float f) {
    unsigned u = __builtin_bit_cast(unsigned, f);
    u += 0x7FFFu + ((u >> 16) & 1u);   // RNE
    return (unsigned short)(u >> 16);
}
__device__ __forceinline__ float bf2f(unsigned short h) {
    unsigned u = ((unsigned)h) << 16;
    return __builtin_bit_cast(float, u);
}

#define GLOAD_LDS16(gsrc, ldst)                                                        \
    __builtin_amdgcn_global_load_lds((const __attribute__((address_space(1))) void*)(gsrc), \
                                     (__attribute__((address_space(3))) void*)(ldst), 16, 0, 0)

// ------------------------------------------------------------------
// Edge dtype detection: int64 input => odd 32-bit words all zero.
// ------------------------------------------------------------------
__global__ void detect_kernel(const unsigned int* __restrict__ edges, int* flag) {
    unsigned v = 0;
    for (int i = threadIdx.x * 2 + 1; i < 2048; i += 512) v |= edges[i];
    if (v) atomicOr(flag, 1);
}

__global__ void convert_count_kernel(const void* __restrict__ edges, const int* __restrict__ flag,
                                     int* __restrict__ src, int* __restrict__ dst,
                                     int* __restrict__ counts, int E) {
    int e = blockIdx.x * 256 + threadIdx.x;
    if (e >= E) return;
    int s, d;
    if (*flag) {  // int32
        const int* p = (const int*)edges;
        s = p[e];
        d = p[E + e];
    } else {      // int64
        const long long* p = (const long long*)edges;
        s = (int)p[e];
        d = (int)p[E + e];
    }
    src[e] = s;
    dst[e] = d;
    atomicAdd(&counts[d], 1);
}

__global__ void dinv_kernel(const int* __restrict__ counts, float* __restrict__ dinv, int n) {
    int i = blockIdx.x * 256 + threadIdx.x;
    if (i < n) dinv[i] = rsqrtf((float)counts[i] + 1.0f);
}

// ---------------- hierarchical exclusive scan ----------------
__global__ void blocksum_kernel(const int* __restrict__ counts, int* __restrict__ bs, int n) {
    __shared__ int sdata[256];
    int i = blockIdx.x * 256 + threadIdx.x;
    sdata[threadIdx.x] = (i < n) ? counts[i] : 0;
    __syncthreads();
    #pragma unroll
    for (int off = 128; off > 0; off >>= 1) {
        if (threadIdx.x < off) sdata[threadIdx.x] += sdata[threadIdx.x + off];
        __syncthreads();
    }
    if (threadIdx.x == 0) bs[blockIdx.x] = sdata[0];
}

__global__ void scanbs_kernel(const int* __restrict__ bs, int* __restrict__ bsoff, int nb) {
    __shared__ int sdata[256];
    int tid = threadIdx.x;
    int v = (tid < nb) ? bs[tid] : 0;
    sdata[tid] = v;
    __syncthreads();
    #pragma unroll
    for (int off = 1; off < 256; off <<= 1) {
        int t = (tid >= off) ? sdata[tid - off] : 0;
        __syncthreads();
        sdata[tid] += t;
        __syncthreads();
    }
    if (tid < nb) bsoff[tid] = sdata[tid] - v;
}

__global__ void scanblock_kernel(const int* __restrict__ counts, const int* __restrict__ bsoff,
                                 int* __restrict__ rowptr, int* __restrict__ cursor, int n) {
    __shared__ int sdata[256];
    int tid = threadIdx.x;
    int i = blockIdx.x * 256 + tid;
    int v = (i < n) ? counts[i] : 0;
    sdata[tid] = v;
    __syncthreads();
    #pragma unroll
    for (int off = 1; off < 256; off <<= 1) {
        int t = (tid >= off) ? sdata[tid - off] : 0;
        __syncthreads();
        sdata[tid] += t;
        __syncthreads();
    }
    int excl = bsoff[blockIdx.x] + sdata[tid] - v;
    if (i < n) { rowptr[i] = excl; cursor[i] = excl; }
    if (i == n - 1) rowptr[n] = excl + v;
}

__global__ void fill_kernel(const int* __restrict__ src, const int* __restrict__ dst,
                            const float* __restrict__ dinv, int* __restrict__ cursor,
                            int* __restrict__ csr_src, float* __restrict__ csr_w, int E) {
    int e = blockIdx.x * 256 + threadIdx.x;
    if (e >= E) return;
    int s = src[e], d = dst[e];
    int pos = atomicAdd(&cursor[d], 1);
    csr_src[pos] = s;
    csr_w[pos] = dinv[s] * dinv[d];
}

// ------------------------------------------------------------------
// Weight split: W -> Wh (bf16 RNE) + Wl (bf16 of residual)
// ------------------------------------------------------------------
__global__ void wsplit_kernel(const float* __restrict__ W, short* __restrict__ Wh,
                              short* __restrict__ Wl, int n) {
    int i = blockIdx.x * 256 + threadIdx.x;
    if (i >= n) return;
    float w = W[i];
    unsigned short h = f2bf_u(w);
    Wh[i] = (short)h;
    Wl[i] = (short)f2bf_u(w - bf2f(h));
}

// ------------------------------------------------------------------
// LDS-staged MFMA GEMM (m97 structure), 512 threads = 8 waves (4x2),
// BM=128, BK=64, wave tile 32 x (BN/2).
// LDS XOR-swizzle in 16B units: unit(row,kg) at kg^(row&7); B staged with
// linear global_load_lds dest + inverse-swizzled global source (rule #21).
// ------------------------------------------------------------------
template<int BN, int KDIM, int LDC, bool AF32, bool RELU, bool OUTBF16>
__global__ __launch_bounds__(512)
void gemm_lds(const void* __restrict__ Av, const short* __restrict__ Bh,
              const short* __restrict__ Bl, const float* __restrict__ bias,
              void* __restrict__ Cv, int M) {
    constexpr int BM = 128, BK = 64;
    constexpr int MI = 2;             // wave rows = 32
    constexpr int NI = BN / 32;       // wave cols = BN/2
    constexpr int BPASS = BN / 64;    // B row-passes per array (8 rows/wave/pass)
    __shared__ short sA[BM * BK];
    __shared__ short sBh[BN * BK];
    __shared__ short sBl[BN * BK];

    const int tid  = threadIdx.x;
    const int lane = tid & 63;
    const int wave = tid >> 6;        // 0..7
    const int wr = wave >> 1, wc = wave & 1;
    const int m0 = blockIdx.x * BM;
    const int n0 = blockIdx.y * BN;
    const int lr = lane & 15;
    const int lk = lane >> 4;
    const int tr = tid >> 3;          // 0..63 staging row
    const int tk = tid & 7;           // staging 16B-unit
    const int l8r = lane >> 3;        // 0..7 row-within-wave for DMA src
    const int l8u = lane & 7;         // unit for DMA src

    f32x4 acc[MI][NI];
    #pragma unroll
    for (int mi = 0; mi < MI; ++mi)
        #pragma unroll
        for (int ni = 0; ni < NI; ++ni) acc[mi][ni] = {0.f, 0.f, 0.f, 0.f};

    #pragma unroll 1
    for (int k0 = 0; k0 < KDIM; k0 += BK) {
        // ---- stage A (128 rows x 64 k) ----
        if (AF32) {
            #pragma unroll
            for (int p = 0; p < 2; ++p) {
                int row = p * 64 + tr;
                int grow = m0 + row; if (grow > M - 1) grow = M - 1;
                const float* s = (const float*)Av + (size_t)grow * KDIM + k0 + tk * 8;
                float4 v0 = *reinterpret_cast<const float4*>(s);
                float4 v1 = *reinterpret_cast<const float4*>(s + 4);
                short8 sh;
                sh[0] = (short)f2bf_u(v0.x); sh[1] = (short)f2bf_u(v0.y);
                sh[2] = (short)f2bf_u(v0.z); sh[3] = (short)f2bf_u(v0.w);
                sh[4] = (short)f2bf_u(v1.x); sh[5] = (short)f2bf_u(v1.y);
                sh[6] = (short)f2bf_u(v1.z); sh[7] = (short)f2bf_u(v1.w);
                *reinterpret_cast<short8*>(&sA[row * 64 + ((tk ^ (row & 7)) << 3)]) = sh;
            }
        } else {
            #pragma unroll
            for (int p = 0; p < 2; ++p) {
                int row = p * 64 + wave * 8 + l8r;
                int grow = m0 + row; if (grow > M - 1) grow = M - 1;
                const short* s = (const short*)Av + (size_t)grow * KDIM + k0 + ((l8u ^ (row & 7)) << 3);
                GLOAD_LDS16(s, &sA[(p * 64 + wave * 8) * 64]);
            }
        }
        // ---- stage Bh/Bl (BN rows x 64 k) via async DMA ----
        #pragma unroll
        for (int p = 0; p < BPASS; ++p) {
            int row = p * 64 + wave * 8 + l8r;
            size_t goff = (size_t)(n0 + row) * KDIM + k0 + ((l8u ^ (row & 7)) << 3);
            GLOAD_LDS16(Bh + goff, &sBh[(p * 64 + wave * 8) * 64]);
            GLOAD_LDS16(Bl + goff, &sBl[(p * 64 + wave * 8) * 64]);
        }
        __syncthreads();   // drains vmcnt+lgkmcnt

        // ---- compute ----
        #pragma unroll
        for (int ks = 0; ks < 2; ++ks) {
            int kg = ks * 4 + lk;
            bf16x8 af[MI], bhf[NI], blf[NI];
            #pragma unroll
            for (int mi = 0; mi < MI; ++mi) {
                int row = wr * 32 + mi * 16 + lr;
                af[mi] = *reinterpret_cast<const bf16x8*>(&sA[row * 64 + ((kg ^ (row & 7)) << 3)]);
            }
            #pragma unroll
            for (int ni = 0; ni < NI; ++ni) {
                int row = wc * (BN / 2) + ni * 16 + lr;
                int idx = row * 64 + ((kg ^ (row & 7)) << 3);
                bhf[ni] = *reinterpret_cast<const bf16x8*>(&sBh[idx]);
                blf[ni] = *reinterpret_cast<const bf16x8*>(&sBl[idx]);
            }
            #pragma unroll
            for (int mi = 0; mi < MI; ++mi)
                #pragma unroll
                for (int ni = 0; ni < NI; ++ni) {
                    acc[mi][ni] = __builtin_amdgcn_mfma_f32_16x16x32_bf16(af[mi], bhf[ni], acc[mi][ni], 0, 0, 0);
                    acc[mi][ni] = __builtin_amdgcn_mfma_f32_16x16x32_bf16(af[mi], blf[ni], acc[mi][ni], 0, 0, 0);
                }
        }
        __syncthreads();
    }

    // ---- epilogue ----
    #pragma unroll
    for (int ni = 0; ni < NI; ++ni) {
        int col = n0 + wc * (BN / 2) + ni * 16 + lr;
        float bv = bias[col];
        #pragma unroll
        for (int mi = 0; mi < MI; ++mi) {
            #pragma unroll
            for (int r = 0; r < 4; ++r) {
                int row = m0 + wr * 32 + mi * 16 + lk * 4 + r;
                if (row < M) {
                    float v = acc[mi][ni][r] + bv;
                    if (RELU) v = fmaxf(v, 0.0f);
                    if (OUTBF16) ((short*)Cv)[(size_t)row * LDC + col] = (short)f2bf_u(v);
                    else         ((float*)Cv)[(size_t)row * LDC + col] = v;
                }
            }
        }
    }
}

// ------------------------------------------------------------------
// Propagation step: one wave per node, lane = channel; 16-edge batched gather.
// ------------------------------------------------------------------
__global__ __launch_bounds__(256)
void prop_kernel(const float* __restrict__ hin, const float* __restrict__ z,
                 const int* __restrict__ rowptr, const int* __restrict__ csr_src,
                 const float* __restrict__ csr_w, const float* __restrict__ dinv,
                 float* __restrict__ hout, int n) {
    int node = blockIdx.x * 4 + (threadIdx.x >> 6);
    int lane = threadIdx.x & 63;
    if (node >= n) return;
    float di = dinv[node];
    int base = node << 6;
    float acc = hin[base + lane] * (di * di);
    int e  = rowptr[node];
    int e1 = rowptr[node + 1];

    for (; e + 16 <= e1; e += 16) {
        int s[16]; float ww[16], v[16];
        #pragma unroll
        for (int j = 0; j < 16; ++j) { s[j] = csr_src[e + j]; ww[j] = csr_w[e + j]; }
        #pragma unroll
        for (int j = 0; j < 16; ++j) v[j] = hin[(s[j] << 6) + lane];
        #pragma unroll
        for (int j = 0; j < 16; ++j) acc = fmaf(v[j], ww[j], acc);
    }
    for (; e + 4 <= e1; e += 4) {
        int s[4]; float ww[4], v[4];
        #pragma unroll
        for (int j = 0; j < 4; ++j) { s[j] = csr_src[e + j]; ww[j] = csr_w[e + j]; }
        #pragma unroll
        for (int j = 0; j < 4; ++j) v[j] = hin[(s[j] << 6) + lane];
        #pragma unroll
        for (int j = 0; j < 4; ++j) acc = fmaf(v[j], ww[j], acc);
    }
    for (; e < e1; ++e) {
        acc = fmaf(hin[(csr_src[e] << 6) + lane], csr_w[e], acc);
    }
    hout[base + lane] = 0.9f * acc + 0.1f * z[base + lane];
}

// ------------------------------------------------------------------
extern "C" void kernel_launch(void* const* d_in, const int* in_sizes, int n_in,
                              void* d_out, int out_size, void* d_ws, size_t ws_size,
                              hipStream_t stream) {
    const float* x  = (const float*)d_in[0];
    const void*  ei = d_in[1];
    const float* W1 = (const float*)d_in[2];
    const float* b1 = (const float*)d_in[3];
    const float* W2 = (const float*)d_in[4];
    const float* b2 = (const float*)d_in[5];
    float* dout = (float*)d_out;

    const int IN_C = 512, HID_C = 256, OUT_C = 64, Ksteps = 10;
    const int N = in_sizes[0] / IN_C;   // 50000
    const int E = in_sizes[1] / 2;      // 800000

    char* w = (char*)d_ws;
    auto alloc = [&](size_t bytes) { char* p = w; w += (bytes + 255) & ~(size_t)255; return p; };
    int*   flag    = (int*)  alloc(4);
    int*   src32   = (int*)  alloc((size_t)E * 4);
    int*   dst32   = (int*)  alloc((size_t)E * 4);
    int*   counts  = (int*)  alloc((size_t)N * 4);
    int*   rowptr  = (int*)  alloc((size_t)(N + 1) * 4);
    int*   cursor  = (int*)  alloc((size_t)N * 4);
    float* dinv    = (float*)alloc((size_t)N * 4);
    int*   csr_src = (int*)  alloc((size_t)E * 4);
    float* csr_w   = (float*)alloc((size_t)E * 4);
    short* W1h     = (short*)alloc((size_t)HID_C * IN_C * 2);
    short* W1l     = (short*)alloc((size_t)HID_C * IN_C * 2);
    short* W2h     = (short*)alloc((size_t)OUT_C * HID_C * 2);
    short* W2l     = (short*)alloc((size_t)OUT_C * HID_C * 2);
    short* Hbf     = (short*)alloc((size_t)N * HID_C * 2);
    float* zbuf    = (float*)alloc((size_t)N * OUT_C * 4);
    float* hB      = (float*)alloc((size_t)N * OUT_C * 4);
    int nblk = (N + 255) / 256;
    int*   bs      = (int*)  alloc((size_t)nblk * 4);
    int*   bsoff   = (int*)  alloc((size_t)nblk * 4);

    hipMemsetAsync(flag, 0, 4, stream);
    hipMemsetAsync(counts, 0, (size_t)N * 4, stream);

    int egrid = (E + 255) / 256;

    // weight splits (tiny)
    wsplit_kernel<<<(HID_C * IN_C + 255) / 256, 256, 0, stream>>>(W1, W1h, W1l, HID_C * IN_C);
    wsplit_kernel<<<(OUT_C * HID_C + 255) / 256, 256, 0, stream>>>(W2, W2h, W2l, OUT_C * HID_C);

    // graph preprocessing
    detect_kernel<<<1, 256, 0, stream>>>((const unsigned int*)ei, flag);
    convert_count_kernel<<<egrid, 256, 0, stream>>>(ei, flag, src32, dst32, counts, E);
    dinv_kernel<<<nblk, 256, 0, stream>>>(counts, dinv, N);
    blocksum_kernel<<<nblk, 256, 0, stream>>>(counts, bs, N);
    scanbs_kernel<<<1, 256, 0, stream>>>(bs, bsoff, nblk);
    scanblock_kernel<<<nblk, 256, 0, stream>>>(counts, bsoff, rowptr, cursor, N);
    fill_kernel<<<egrid, 256, 0, stream>>>(src32, dst32, dinv, cursor, csr_src, csr_w, E);

    // MLP on matrix cores (LDS-staged MFMA, 8-wave blocks)
    int mgrid = (N + 127) / 128;
    dim3 g1(mgrid, 2);   // BN=128, N-total=256
    gemm_lds<128, 512, 256, true, true, true>
        <<<g1, 512, 0, stream>>>(x, W1h, W1l, b1, Hbf, N);
    dim3 g2(mgrid, 1);   // BN=64 = full N
    gemm_lds<64, 256, 64, false, false, false>
        <<<g2, 512, 0, stream>>>(Hbf, W2h, W2l, b2, zbuf, N);

    // K propagation steps. h^(0) = z lives in zbuf; steps ping-pong hB/dout,
    // ending in dout at s=9 (odd steps write dout).
    int pgrid = (N + 3) / 4;
    for (int s = 0; s < Ksteps; ++s) {
        const float* in  = (s == 0) ? zbuf : ((s & 1) ? hB : dout);
        float*       out = (s & 1) ? dout : hB;
        prop_kernel<<<pgrid, 256, 0, stream>>>(in, zbuf, rowptr, csr_src, csr_w, dinv, out, N);
    }
}

// Round 6
// 530.050 us; speedup vs baseline: 1.0163x; 1.0163x over previous
//
#include <hip/hip_runtime.h>

typedef __bf16 bf16x8 __attribute__((ext_vector_type(8)));
typedef float f32x4 __attribute__((ext_vector_type(4)));
typedef short short8 __attribute__((ext_vector_type(8)));

__device__ __forceinline__ unsigned short f2bf_u(float f) {
    unsigned u = __builtin_bit_cast(unsigned, f);
    u += 0x7FFFu + ((u >> 16) & 1u);   // RNE
    return (unsigned short)(u >> 16);
}
__device__ __forceinline__ float bf2f(unsigned short h) {
    unsigned u = ((unsigned)h) << 16;
    return __builtin_bit_cast(float, u);
}

#define GLOAD_LDS16(gsrc, ldst)                                                        \
    __builtin_amdgcn_global_load_lds((const __attribute__((address_space(1))) void*)(gsrc), \
                                     (__attribute__((address_space(3))) void*)(ldst), 16, 0, 0)

// ------------------------------------------------------------------
// Edge dtype detection: int64 input => odd 32-bit words all zero.
// ------------------------------------------------------------------
__global__ void detect_kernel(const unsigned int* __restrict__ edges, int* flag) {
    unsigned v = 0;
    for (int i = threadIdx.x * 2 + 1; i < 2048; i += 512) v |= edges[i];
    if (v) atomicOr(flag, 1);
}

__global__ void convert_count_kernel(const void* __restrict__ edges, const int* __restrict__ flag,
                                     int* __restrict__ src, int* __restrict__ dst,
                                     int* __restrict__ counts, int E) {
    int e = blockIdx.x * 256 + threadIdx.x;
    if (e >= E) return;
    int s, d;
    if (*flag) {  // int32
        const int* p = (const int*)edges;
        s = p[e];
        d = p[E + e];
    } else {      // int64
        const long long* p = (const long long*)edges;
        s = (int)p[e];
        d = (int)p[E + e];
    }
    src[e] = s;
    dst[e] = d;
    atomicAdd(&counts[d], 1);
}

__global__ void dinv_kernel(const int* __restrict__ counts, float* __restrict__ dinv, int n) {
    int i = blockIdx.x * 256 + threadIdx.x;
    if (i < n) dinv[i] = rsqrtf((float)counts[i] + 1.0f);
}

// ---------------- hierarchical exclusive scan ----------------
__global__ void blocksum_kernel(const int* __restrict__ counts, int* __restrict__ bs, int n) {
    __shared__ int sdata[256];
    int i = blockIdx.x * 256 + threadIdx.x;
    sdata[threadIdx.x] = (i < n) ? counts[i] : 0;
    __syncthreads();
    #pragma unroll
    for (int off = 128; off > 0; off >>= 1) {
        if (threadIdx.x < off) sdata[threadIdx.x] += sdata[threadIdx.x + off];
        __syncthreads();
    }
    if (threadIdx.x == 0) bs[blockIdx.x] = sdata[0];
}

__global__ void scanbs_kernel(const int* __restrict__ bs, int* __restrict__ bsoff, int nb) {
    __shared__ int sdata[256];
    int tid = threadIdx.x;
    int v = (tid < nb) ? bs[tid] : 0;
    sdata[tid] = v;
    __syncthreads();
    #pragma unroll
    for (int off = 1; off < 256; off <<= 1) {
        int t = (tid >= off) ? sdata[tid - off] : 0;
        __syncthreads();
        sdata[tid] += t;
        __syncthreads();
    }
    if (tid < nb) bsoff[tid] = sdata[tid] - v;
}

__global__ void scanblock_kernel(const int* __restrict__ counts, const int* __restrict__ bsoff,
                                 int* __restrict__ rowptr, int* __restrict__ cursor, int n) {
    __shared__ int sdata[256];
    int tid = threadIdx.x;
    int i = blockIdx.x * 256 + tid;
    int v = (i < n) ? counts[i] : 0;
    sdata[tid] = v;
    __syncthreads();
    #pragma unroll
    for (int off = 1; off < 256; off <<= 1) {
        int t = (tid >= off) ? sdata[tid - off] : 0;
        __syncthreads();
        sdata[tid] += t;
        __syncthreads();
    }
    int excl = bsoff[blockIdx.x] + sdata[tid] - v;
    if (i < n) { rowptr[i] = excl; cursor[i] = excl; }
    if (i == n - 1) rowptr[n] = excl + v;
}

__global__ void fill_kernel(const int* __restrict__ src, const int* __restrict__ dst,
                            const float* __restrict__ dinv, int* __restrict__ cursor,
                            int* __restrict__ csr_src, float* __restrict__ csr_w, int E) {
    int e = blockIdx.x * 256 + threadIdx.x;
    if (e >= E) return;
    int s = src[e], d = dst[e];
    int pos = atomicAdd(&cursor[d], 1);
    csr_src[pos] = s;
    csr_w[pos] = dinv[s] * dinv[d];
}

// ------------------------------------------------------------------
// Weight split: W -> Wh (bf16 RNE) + Wl (bf16 of residual)
// ------------------------------------------------------------------
__global__ void wsplit_kernel(const float* __restrict__ W, short* __restrict__ Wh,
                              short* __restrict__ Wl, int n) {
    int i = blockIdx.x * 256 + threadIdx.x;
    if (i >= n) return;
    float w = W[i];
    unsigned short h = f2bf_u(w);
    Wh[i] = (short)h;
    Wl[i] = (short)f2bf_u(w - bf2f(h));
}

// ------------------------------------------------------------------
// x fp32 -> bf16 streaming conversion (8 elems/thread/iter)
// ------------------------------------------------------------------
__global__ __launch_bounds__(256)
void cvtbf_kernel(const float* __restrict__ x, short* __restrict__ out, int n8) {
    for (int i = blockIdx.x * 256 + threadIdx.x; i < n8; i += gridDim.x * 256) {
        const float4* p = reinterpret_cast<const float4*>(x + (size_t)i * 8);
        float4 v0 = p[0], v1 = p[1];
        short8 s;
        s[0] = (short)f2bf_u(v0.x); s[1] = (short)f2bf_u(v0.y);
        s[2] = (short)f2bf_u(v0.z); s[3] = (short)f2bf_u(v0.w);
        s[4] = (short)f2bf_u(v1.x); s[5] = (short)f2bf_u(v1.y);
        s[6] = (short)f2bf_u(v1.z); s[7] = (short)f2bf_u(v1.w);
        *reinterpret_cast<short8*>(out + (size_t)i * 8) = s;
    }
}

// ------------------------------------------------------------------
// Double-buffered MFMA GEMM, 2-phase prefetch-ahead (T3-minimum recipe):
//   prologue: STAGE(buf0,0); vmcnt(0); barrier
//   loop: STAGE(buf^1, t+1); compute(buf); vmcnt(0); s_barrier
// BM=128, BN=64, BK=64, 512 threads (8 waves, 4x2), all staging via
// global_load_lds w=16, XOR-swizzled (16B unit kg^(row&7), conflict-free).
// A bf16, Bh/Bl bf16 split weights, C bf16.
// ------------------------------------------------------------------
template<int KDIM, int LDC, bool RELU>
__global__ __launch_bounds__(512)
void gemm_db(const short* __restrict__ A, const short* __restrict__ Bh,
             const short* __restrict__ Bl, const float* __restrict__ bias,
             short* __restrict__ C, int M) {
    constexpr int BM = 128, BN = 64, BK = 64;
    constexpr int NT = KDIM / BK;
    __shared__ short sA[2][BM * BK];
    __shared__ short sB[2][2][BN * BK];

    const int tid  = threadIdx.x;
    const int lane = tid & 63;
    const int wave = tid >> 6;        // 0..7
    const int wr = wave >> 1, wc = wave & 1;
    const int m0 = blockIdx.x * BM;
    const int n0 = blockIdx.y * BN;
    const int lr = lane & 15;
    const int lk = lane >> 4;
    const int l8r = lane >> 3;        // 0..7
    const int l8u = lane & 7;         // 16B unit

    f32x4 acc[2][2];
    #pragma unroll
    for (int mi = 0; mi < 2; ++mi)
        #pragma unroll
        for (int ni = 0; ni < 2; ++ni) acc[mi][ni] = {0.f, 0.f, 0.f, 0.f};

    auto stage = [&](int buf, int k0) {
        #pragma unroll
        for (int p = 0; p < 2; ++p) {
            int row = p * 64 + wave * 8 + l8r;
            int grow = m0 + row; if (grow > M - 1) grow = M - 1;
            const short* s = A + (size_t)grow * KDIM + k0 + ((l8u ^ (row & 7)) << 3);
            GLOAD_LDS16(s, &sA[buf][p * 4096 + wave * 512]);
        }
        int row = wave * 8 + l8r;
        size_t goff = (size_t)(n0 + row) * KDIM + k0 + ((l8u ^ (row & 7)) << 3);
        GLOAD_LDS16(Bh + goff, &sB[buf][0][wave * 512]);
        GLOAD_LDS16(Bl + goff, &sB[buf][1][wave * 512]);
    };

    stage(0, 0);
    asm volatile("s_waitcnt vmcnt(0)" ::: "memory");
    __builtin_amdgcn_s_barrier();
    asm volatile("" ::: "memory");

    int cur = 0;
    #pragma unroll 1
    for (int t = 0; t < NT; ++t) {
        if (t + 1 < NT) stage(cur ^ 1, (t + 1) * BK);   // prefetch next tile
        #pragma unroll
        for (int ks = 0; ks < 2; ++ks) {
            int kg = ks * 4 + lk;
            bf16x8 af[2], bhf[2], blf[2];
            #pragma unroll
            for (int mi = 0; mi < 2; ++mi) {
                int row = wr * 32 + mi * 16 + lr;
                af[mi] = *reinterpret_cast<const bf16x8*>(&sA[cur][row * 64 + ((kg ^ (row & 7)) << 3)]);
            }
            #pragma unroll
            for (int ni = 0; ni < 2; ++ni) {
                int row = wc * 32 + ni * 16 + lr;
                int idx = row * 64 + ((kg ^ (row & 7)) << 3);
                bhf[ni] = *reinterpret_cast<const bf16x8*>(&sB[cur][0][idx]);
                blf[ni] = *reinterpret_cast<const bf16x8*>(&sB[cur][1][idx]);
            }
            #pragma unroll
            for (int mi = 0; mi < 2; ++mi)
                #pragma unroll
                for (int ni = 0; ni < 2; ++ni) {
                    acc[mi][ni] = __builtin_amdgcn_mfma_f32_16x16x32_bf16(af[mi], bhf[ni], acc[mi][ni], 0, 0, 0);
                    acc[mi][ni] = __builtin_amdgcn_mfma_f32_16x16x32_bf16(af[mi], blf[ni], acc[mi][ni], 0, 0, 0);
                }
        }
        asm volatile("s_waitcnt vmcnt(0)" ::: "memory");   // prefetch landed (had compute-time)
        __builtin_amdgcn_s_barrier();
        asm volatile("" ::: "memory");
        cur ^= 1;
    }

    // epilogue
    #pragma unroll
    for (int ni = 0; ni < 2; ++ni) {
        int col = n0 + wc * 32 + ni * 16 + lr;
        float bv = bias[col];
        #pragma unroll
        for (int mi = 0; mi < 2; ++mi) {
            #pragma unroll
            for (int r = 0; r < 4; ++r) {
                int row = m0 + wr * 32 + mi * 16 + lk * 4 + r;
                if (row < M) {
                    float v = acc[mi][ni][r] + bv;
                    if (RELU) v = fmaxf(v, 0.0f);
                    C[(size_t)row * LDC + col] = (short)f2bf_u(v);
                }
            }
        }
    }
}

// ------------------------------------------------------------------
// Propagation step, bf16 storage / fp32 accumulate.
// One wave per node, lane = channel; 16-edge batched gather (128B rows).
// ------------------------------------------------------------------
template<bool OUTF32>
__global__ __launch_bounds__(256)
void prop_bf16(const unsigned short* __restrict__ hin, const unsigned short* __restrict__ zb,
               const int* __restrict__ rowptr, const int* __restrict__ csr_src,
               const float* __restrict__ csr_w, const float* __restrict__ dinv,
               void* __restrict__ hout, int n) {
    int node = blockIdx.x * 4 + (threadIdx.x >> 6);
    int lane = threadIdx.x & 63;
    if (node >= n) return;
    float di = dinv[node];
    int base = node << 6;
    float acc = bf2f(hin[base + lane]) * (di * di);
    int e  = rowptr[node];
    int e1 = rowptr[node + 1];

    for (; e + 16 <= e1; e += 16) {
        int s[16]; float ww[16]; unsigned short v[16];
        #pragma unroll
        for (int j = 0; j < 16; ++j) { s[j] = csr_src[e + j]; ww[j] = csr_w[e + j]; }
        #pragma unroll
        for (int j = 0; j < 16; ++j) v[j] = hin[(s[j] << 6) + lane];
        #pragma unroll
        for (int j = 0; j < 16; ++j) acc = fmaf(bf2f(v[j]), ww[j], acc);
    }
    for (; e + 4 <= e1; e += 4) {
        int s[4]; float ww[4]; unsigned short v[4];
        #pragma unroll
        for (int j = 0; j < 4; ++j) { s[j] = csr_src[e + j]; ww[j] = csr_w[e + j]; }
        #pragma unroll
        for (int j = 0; j < 4; ++j) v[j] = hin[(s[j] << 6) + lane];
        #pragma unroll
        for (int j = 0; j < 4; ++j) acc = fmaf(bf2f(v[j]), ww[j], acc);
    }
    for (; e < e1; ++e) {
        acc = fmaf(bf2f(hin[(csr_src[e] << 6) + lane]), csr_w[e], acc);
    }
    float res = 0.9f * acc + 0.1f * bf2f(zb[base + lane]);
    if (OUTF32) ((float*)hout)[base + lane] = res;
    else        ((unsigned short*)hout)[base + lane] = f2bf_u(res);
}

// ------------------------------------------------------------------
extern "C" void kernel_launch(void* const* d_in, const int* in_sizes, int n_in,
                              void* d_out, int out_size, void* d_ws, size_t ws_size,
                              hipStream_t stream) {
    const float* x  = (const float*)d_in[0];
    const void*  ei = d_in[1];
    const float* W1 = (const float*)d_in[2];
    const float* b1 = (const float*)d_in[3];
    const float* W2 = (const float*)d_in[4];
    const float* b2 = (const float*)d_in[5];
    float* dout = (float*)d_out;

    const int IN_C = 512, HID_C = 256, OUT_C = 64, Ksteps = 10;
    const int N = in_sizes[0] / IN_C;   // 50000
    const int E = in_sizes[1] / 2;      // 800000

    char* w = (char*)d_ws;
    auto alloc = [&](size_t bytes) { char* p = w; w += (bytes + 255) & ~(size_t)255; return p; };
    int*   flag    = (int*)  alloc(4);
    int*   src32   = (int*)  alloc((size_t)E * 4);
    int*   dst32   = (int*)  alloc((size_t)E * 4);
    int*   counts  = (int*)  alloc((size_t)N * 4);
    int*   rowptr  = (int*)  alloc((size_t)(N + 1) * 4);
    int*   cursor  = (int*)  alloc((size_t)N * 4);
    float* dinv    = (float*)alloc((size_t)N * 4);
    int*   csr_src = (int*)  alloc((size_t)E * 4);
    float* csr_w   = (float*)alloc((size_t)E * 4);
    short* W1h     = (short*)alloc((size_t)HID_C * IN_C * 2);
    short* W1l     = (short*)alloc((size_t)HID_C * IN_C * 2);
    short* W2h     = (short*)alloc((size_t)OUT_C * HID_C * 2);
    short* W2l     = (short*)alloc((size_t)OUT_C * HID_C * 2);
    short* xbf     = (short*)alloc((size_t)N * IN_C * 2);
    short* Hbf     = (short*)alloc((size_t)N * HID_C * 2);
    unsigned short* zbf = (unsigned short*)alloc((size_t)N * OUT_C * 2);
    unsigned short* hA  = (unsigned short*)alloc((size_t)N * OUT_C * 2);
    unsigned short* hB  = (unsigned short*)alloc((size_t)N * OUT_C * 2);
    int nblk = (N + 255) / 256;
    int*   bs      = (int*)  alloc((size_t)nblk * 4);
    int*   bsoff   = (int*)  alloc((size_t)nblk * 4);

    hipMemsetAsync(flag, 0, 4, stream);
    hipMemsetAsync(counts, 0, (size_t)N * 4, stream);

    int egrid = (E + 255) / 256;

    // x -> bf16 (streaming)
    cvtbf_kernel<<<2048, 256, 0, stream>>>(x, xbf, N * IN_C / 8);

    // weight splits (tiny)
    wsplit_kernel<<<(HID_C * IN_C + 255) / 256, 256, 0, stream>>>(W1, W1h, W1l, HID_C * IN_C);
    wsplit_kernel<<<(OUT_C * HID_C + 255) / 256, 256, 0, stream>>>(W2, W2h, W2l, OUT_C * HID_C);

    // graph preprocessing
    detect_kernel<<<1, 256, 0, stream>>>((const unsigned int*)ei, flag);
    convert_count_kernel<<<egrid, 256, 0, stream>>>(ei, flag, src32, dst32, counts, E);
    dinv_kernel<<<nblk, 256, 0, stream>>>(counts, dinv, N);
    blocksum_kernel<<<nblk, 256, 0, stream>>>(counts, bs, N);
    scanbs_kernel<<<1, 256, 0, stream>>>(bs, bsoff, nblk);
    scanblock_kernel<<<nblk, 256, 0, stream>>>(counts, bsoff, rowptr, cursor, N);
    fill_kernel<<<egrid, 256, 0, stream>>>(src32, dst32, dinv, cursor, csr_src, csr_w, E);

    // MLP on matrix cores (double-buffered DMA-staged MFMA)
    int mgrid = (N + 127) / 128;
    gemm_db<512, 256, true><<<dim3(mgrid, 4), 512, 0, stream>>>(xbf, W1h, W1l, b1, Hbf, N);
    gemm_db<256, 64, false><<<dim3(mgrid, 1), 512, 0, stream>>>(Hbf, W2h, W2l, b2, (short*)zbf, N);

    // K propagation steps in bf16 (h^(0)=z in zbf); final step writes fp32 dout.
    int pgrid = (N + 3) / 4;
    const unsigned short* pin = zbf;
    for (int s = 0; s < Ksteps - 1; ++s) {
        unsigned short* out = (s & 1) ? hB : hA;
        prop_bf16<false><<<pgrid, 256, 0, stream>>>(pin, zbf, rowptr, csr_src, csr_w, dinv, out, N);
        pin = out;
    }
    prop_bf16<true><<<pgrid, 256, 0, stream>>>(pin, zbf, rowptr, csr_src, csr_w, dinv, dout, N);
}